// Round 2
// baseline (257.204 us; speedup 1.0000x reference)
//
#include <hip/hip_runtime.h>

#define NPIX 16384

typedef _Float16 f16;
typedef __attribute__((ext_vector_type(8))) _Float16 half8;
typedef __attribute__((ext_vector_type(8))) unsigned short ushort8;
typedef __attribute__((ext_vector_type(4))) float f32x4;   // native vec4

// Load 8 consecutive floats (nontemporal), convert to half8 fragment.
__device__ inline half8 cvt8_nt(const float* __restrict__ p) {
  f32x4 a = __builtin_nontemporal_load((const f32x4*)p);
  f32x4 b = __builtin_nontemporal_load((const f32x4*)p + 1);
  half8 r;
  r[0] = (f16)a.x; r[1] = (f16)a.y; r[2] = (f16)a.z; r[3] = (f16)a.w;
  r[4] = (f16)b.x; r[5] = (f16)b.y; r[6] = (f16)b.z; r[7] = (f16)b.w;
  return r;
}
__device__ inline half8 cvt8(const float* __restrict__ p) {
  f32x4 a = *(const f32x4*)p;
  f32x4 b = *(const f32x4*)(p + 4);
  half8 r;
  r[0] = (f16)a.x; r[1] = (f16)a.y; r[2] = (f16)a.z; r[3] = (f16)a.w;
  r[4] = (f16)b.x; r[5] = (f16)b.y; r[6] = (f16)b.z; r[7] = (f16)b.w;
  return r;
}

// Transpose+convert:
//   y [16][8][NPIX] f32 + noise [16][8][NPIX] f32 -> feats[p][b][n] f16 ([NPIX][256], 8 MB)
//   noise2 [16][NPIX][8] f32                      -> n2p[p][b][dm] f16 ([NPIX][128], 4 MB)
__global__ __launch_bounds__(256) void pack_feats(
    const float* __restrict__ y,
    const float* __restrict__ nz,
    const float* __restrict__ nz2,
    f16* __restrict__ outf,
    f16* __restrict__ n2p)
{
  __shared__ f16 tile[64][258];
  const int p0 = blockIdx.x << 6;
  const int t = threadIdx.x;
  const int lane16 = t & 15;
  const int pl0 = t >> 4;
  #pragma unroll
  for (int g = 0; g < 16; ++g) {
    const int plane = g * 16 + pl0;          // plane = b*16 + n
    const int b = plane >> 4, n = plane & 15;
    const float* src = (n < 8) ? (y + (b * 8 + n) * NPIX)
                               : (nz + (b * 8 + (n - 8)) * NPIX);
    f32x4 v = __builtin_nontemporal_load((const f32x4*)(src + p0 + lane16 * 4));
    tile[lane16 * 4 + 0][plane] = (f16)v.x;
    tile[lane16 * 4 + 1][plane] = (f16)v.y;
    tile[lane16 * 4 + 2][plane] = (f16)v.z;
    tile[lane16 * 4 + 3][plane] = (f16)v.w;
  }
  // noise2 pack: wave = one b, 64 consecutive px -> 2 KB contiguous loads.
  // 16 B stores at 256 B stride merge in L2 (same block, near-in-time).
  #pragma unroll
  for (int it = 0; it < 4; ++it) {
    const int pair = it * 256 + t;           // b*64 + pl
    const int b = pair >> 6;
    const int pl = pair & 63;
    half8 v = cvt8_nt(nz2 + (size_t)(b * NPIX + p0 + pl) * 8);
    *(half8*)(n2p + (p0 + pl) * 128 + b * 8) = v;
  }
  __syncthreads();
  #pragma unroll
  for (int it = 0; it < 8; ++it) {
    const int idx = it * 256 + t;
    const int px = idx >> 5;
    const int c = idx & 31;
    ushort8 v = *(const ushort8*)&tile[px][c * 8];
    *(ushort8*)(outf + (p0 + px) * 256 + c * 8) = v;  // cached: re-read by lr_fused
  }
}

// Fused einsum + MLP. One wave per TWO pixels; 4 waves (8 px) per block, grid 2048.
// Two independent wmap/feats load streams per wave are issued before any MFMA
// consumes -> ~2x bytes in flight per wave; per-px fixed costs (nidx, MLP weight
// preloads, block turnover) are halved.
// einsum: D[b][m] = sum_{k,n} feats[b][nb(p,k)][n] * wmap[p][k][m][n]  (K=144 pad 160)
// MFMA f32_16x16x32_f16: A[i=lane&15][k=q*8+j], B[j=lane&15][k], D: col=lane&15, row=q*4+r.
__global__ __launch_bounds__(256, 3) void lr_fused(
    const f16*  __restrict__ feats,   // [NPIX][16][16] f16 (ws)
    const f16*  __restrict__ n2p,     // [NPIX][16][8] f16 (ws)
    const float* __restrict__ wmap,   // [NPIX][9][16][16] f32
    const int*  __restrict__ nidx,    // [NPIX][9] i32
    const float* __restrict__ w1,     // [64][24] f32
    const float* __restrict__ b1,     // [64] f32
    const float* __restrict__ w2,     // [8][64] f32
    const float* __restrict__ b2,     // [8] f32
    float* __restrict__ outp)         // [16][8][NPIX] f32
{
  __shared__ f16 tbuf[4][2][256];                 // per-wave einsum-D transpose (2 px)
  __shared__ f16 lds_h[4][16 * 72];               // per-wave h [b][j] scratch
  __shared__ __align__(16) float stage[128][8];   // out tile [(b*8+f)][8 px]

  const int t = threadIdx.x;
  const int wv = t >> 6;
  const int l = t & 63;
  const int col = l & 15;
  const int q = l >> 4;

  const int bid = blockIdx.x;                               // [0, 2048)
  const int p0 = (((bid & 7) << 8) + (bid >> 3)) << 3;      // XCD-slab swizzle, 8 px/block
  const int pw = p0 + wv * 2;                               // wave's first pixel

  // ---- einsum phase ----
  const int n0 = (q & 1) * 8;
  const int kh = q >> 1;

  const int ps = __builtin_amdgcn_readfirstlane(pw);
  int nb0[9], nb1[9];
  #pragma unroll
  for (int k = 0; k < 9; ++k) {
    nb0[k] = __builtin_amdgcn_readfirstlane(nidx[ps * 9 + k]);
    nb1[k] = __builtin_amdgcn_readfirstlane(nidx[ps * 9 + 9 + k]);
  }

  half8 af0[5], bf0[5], af1[5], bf1[5];
  #pragma unroll
  for (int c = 0; c < 4; ++c) {
    const int k = 2 * c + kh;
    af0[c] = *(const half8*)(feats + nb0[k] * 256 + col * 16 + n0);      // L2-hot gather
    bf0[c] = cvt8_nt(wmap + ((ps * 9 + k) * 16 + col) * 16 + n0);        // streaming, nt
  }
  #pragma unroll
  for (int c = 0; c < 4; ++c) {
    const int k = 2 * c + kh;
    af1[c] = *(const half8*)(feats + nb1[k] * 256 + col * 16 + n0);
    bf1[c] = cvt8_nt(wmap + (((ps + 1) * 9 + k) * 16 + col) * 16 + n0);
  }
  af0[4] = (half8){0, 0, 0, 0, 0, 0, 0, 0};
  bf0[4] = (half8){0, 0, 0, 0, 0, 0, 0, 0};
  af1[4] = (half8){0, 0, 0, 0, 0, 0, 0, 0};
  bf1[4] = (half8){0, 0, 0, 0, 0, 0, 0, 0};
  if (q < 2) {  // kk 128..143 (k=8); 144..159 zero pad
    af0[4] = *(const half8*)(feats + nb0[8] * 256 + col * 16 + n0);
    bf0[4] = cvt8_nt(wmap + ((ps * 9 + 8) * 16 + col) * 16 + n0);
    af1[4] = *(const half8*)(feats + nb1[8] * 256 + col * 16 + n0);
    bf1[4] = cvt8_nt(wmap + (((ps + 1) * 9 + 8) * 16 + col) * 16 + n0);
  }
  f32x4 acc0 = {0.f, 0.f, 0.f, 0.f};
  f32x4 acc1 = {0.f, 0.f, 0.f, 0.f};
  #pragma unroll
  for (int c = 0; c < 5; ++c) {
    acc0 = __builtin_amdgcn_mfma_f32_16x16x32_f16(af0[c], bf0[c], acc0, 0, 0, 0);
    acc1 = __builtin_amdgcn_mfma_f32_16x16x32_f16(af1[c], bf1[c], acc1, 0, 0, 0);
  }

  // D[b=q*4+r][m=col] -> tbuf[b*16+m] (wave-private; same layout 'inter' had)
  f16* tb0 = tbuf[wv][0];
  f16* tb1 = tbuf[wv][1];
  #pragma unroll
  for (int r = 0; r < 4; ++r) {
    tb0[(q * 4 + r) * 16 + col] = (f16)acc0[r];
    tb1[(q * 4 + r) * 16 + col] = (f16)acc1[r];
  }

  // ---- MLP preloads (after einsum MFMAs: af/bf live ranges are dead) ----
  half8 w1f[4];
  float b1f[4];
  #pragma unroll
  for (int jc = 0; jc < 4; ++jc) {
    w1f[jc] = (half8){0, 0, 0, 0, 0, 0, 0, 0};
    if (q < 3) w1f[jc] = cvt8(w1 + (jc * 16 + col) * 24 + q * 8);
    b1f[jc] = b1[jc * 16 + col];
  }
  half8 w2f[2] = {{0, 0, 0, 0, 0, 0, 0, 0}, {0, 0, 0, 0, 0, 0, 0, 0}};
  float b2f = 0.f;
  if (col < 8) {
    w2f[0] = cvt8(w2 + col * 64 + q * 8);
    w2f[1] = cvt8(w2 + col * 64 + 32 + q * 8);
    b2f = b2[col];
  }
  half8 n2v[2] = {{0, 0, 0, 0, 0, 0, 0, 0}, {0, 0, 0, 0, 0, 0, 0, 0}};
  if (q == 2) {
    n2v[0] = *(const half8*)(n2p + pw * 128 + col * 8);        // coalesced, L2-hot
    n2v[1] = *(const half8*)(n2p + (pw + 1) * 128 + col * 8);
  }

  const f32x4 zero4 = {0.f, 0.f, 0.f, 0.f};
  f16* lh = lds_h[wv];

  #pragma unroll
  for (int px = 0; px < 2; ++px) {
    // ---- MLP1: K=24 pad 32, N=64 ----
    half8 amlp = n2v[px];                                    // q==2: noise2; q==3: zero
    if (q < 2) amlp = *(const half8*)(tbuf[wv][px] + col * 16 + q * 8);  // d0..15

    #pragma unroll
    for (int jc = 0; jc < 4; ++jc) {
      f32x4 h4 = __builtin_amdgcn_mfma_f32_16x16x32_f16(amlp, w1f[jc], zero4, 0, 0, 0);
      #pragma unroll
      for (int r = 0; r < 4; ++r) {
        float hv = fmaxf(h4[r] + b1f[jc], 0.f);
        lh[(q * 4 + r) * 72 + jc * 16 + col] = (f16)hv;      // wave-private, no barrier
      }
    }

    // ---- MLP2: K=64, N=8 pad 16 ----
    f32x4 oacc = zero4;
    #pragma unroll
    for (int c2 = 0; c2 < 2; ++c2) {
      half8 a2 = *(const half8*)(lh + col * 72 + c2 * 32 + q * 8);
      oacc = __builtin_amdgcn_mfma_f32_16x16x32_f16(a2, w2f[c2], oacc, 0, 0, 0);
    }
    if (col < 8) {
      const int pxl = wv * 2 + px;
      #pragma unroll
      for (int r = 0; r < 4; ++r) {
        const int row = q * 32 + r * 8 + col;   // b*8 + f
        stage[row][pxl] = oacc[r] + b2f;
      }
    }
  }

  __syncthreads();

  // ---- cooperative write-out: 128 rows x 8 px; 16 B stores; consecutive-p blocks
  // live on the same XCD slab -> L2 merges to full lines before HBM ----
  {
    const int row = t >> 1;
    const int c4 = (t & 1) * 4;
    f32x4 v = *(const f32x4*)&stage[row][c4];
    *(f32x4*)(outp + row * NPIX + p0 + c4) = v;
  }
}

extern "C" void kernel_launch(void* const* d_in, const int* in_sizes, int n_in,
                              void* d_out, int out_size, void* d_ws, size_t ws_size,
                              hipStream_t stream) {
  const float* y    = (const float*)d_in[0];
  const float* nz   = (const float*)d_in[1];
  const float* nz2  = (const float*)d_in[2];
  const float* wmap = (const float*)d_in[3];
  const float* w1   = (const float*)d_in[4];
  const float* b1   = (const float*)d_in[5];
  const float* w2   = (const float*)d_in[6];
  const float* b2   = (const float*)d_in[7];
  const int* nidx   = (const int*)d_in[8];
  float* outp = (float*)d_out;
  f16* feats = (f16*)d_ws;                                        // 8 MB
  f16* n2p   = (f16*)((char*)d_ws + (size_t)NPIX * 256 * 2);      // 4 MB

  hipLaunchKernelGGL(pack_feats, dim3(NPIX / 64), dim3(256), 0, stream,
                     y, nz, nz2, feats, n2p);
  hipLaunchKernelGGL(lr_fused, dim3(NPIX / 8), dim3(256), 0, stream,
                     feats, n2p, wmap, nidx, w1, b1, w2, b2, outp);
}

// Round 3
// 248.137 us; speedup vs baseline: 1.0365x; 1.0365x over previous
//
#include <hip/hip_runtime.h>

#define NPIX 16384

typedef _Float16 f16;
typedef __attribute__((ext_vector_type(8))) _Float16 half8;
typedef __attribute__((ext_vector_type(8))) unsigned short ushort8;
typedef __attribute__((ext_vector_type(4))) float f32x4;   // native vec4
typedef __attribute__((ext_vector_type(2))) float f32x2;

// Load 8 consecutive floats (nontemporal), convert to half8 fragment.
__device__ inline half8 cvt8_nt(const float* __restrict__ p) {
  f32x4 a = __builtin_nontemporal_load((const f32x4*)p);
  f32x4 b = __builtin_nontemporal_load((const f32x4*)p + 1);
  half8 r;
  r[0] = (f16)a.x; r[1] = (f16)a.y; r[2] = (f16)a.z; r[3] = (f16)a.w;
  r[4] = (f16)b.x; r[5] = (f16)b.y; r[6] = (f16)b.z; r[7] = (f16)b.w;
  return r;
}
__device__ inline half8 cvt8(const float* __restrict__ p) {
  f32x4 a = *(const f32x4*)p;
  f32x4 b = *(const f32x4*)(p + 4);
  half8 r;
  r[0] = (f16)a.x; r[1] = (f16)a.y; r[2] = (f16)a.z; r[3] = (f16)a.w;
  r[4] = (f16)b.x; r[5] = (f16)b.y; r[6] = (f16)b.z; r[7] = (f16)b.w;
  return r;
}
__device__ inline half8 cvt8_pair(f32x4 a, f32x4 b) {
  half8 r;
  r[0] = (f16)a.x; r[1] = (f16)a.y; r[2] = (f16)a.z; r[3] = (f16)a.w;
  r[4] = (f16)b.x; r[5] = (f16)b.y; r[6] = (f16)b.z; r[7] = (f16)b.w;
  return r;
}

// Transpose+convert:
//   y [16][8][NPIX] f32 + noise [16][8][NPIX] f32 -> feats[p][b][n] f16 ([NPIX][256], 8 MB)
//   noise2 [16][NPIX][8] f32                      -> n2p[p][b][dm] f16 ([NPIX][128], 4 MB)
__global__ __launch_bounds__(256) void pack_feats(
    const float* __restrict__ y,
    const float* __restrict__ nz,
    const float* __restrict__ nz2,
    f16* __restrict__ outf,
    f16* __restrict__ n2p)
{
  __shared__ f16 tile[64][258];
  const int p0 = blockIdx.x << 6;
  const int t = threadIdx.x;
  const int lane16 = t & 15;
  const int pl0 = t >> 4;
  #pragma unroll
  for (int g = 0; g < 16; ++g) {
    const int plane = g * 16 + pl0;          // plane = b*16 + n
    const int b = plane >> 4, n = plane & 15;
    const float* src = (n < 8) ? (y + (b * 8 + n) * NPIX)
                               : (nz + (b * 8 + (n - 8)) * NPIX);
    f32x4 v = __builtin_nontemporal_load((const f32x4*)(src + p0 + lane16 * 4));
    tile[lane16 * 4 + 0][plane] = (f16)v.x;
    tile[lane16 * 4 + 1][plane] = (f16)v.y;
    tile[lane16 * 4 + 2][plane] = (f16)v.z;
    tile[lane16 * 4 + 3][plane] = (f16)v.w;
  }
  // noise2 pack: wave = one b, 64 consecutive px -> 2 KB contiguous loads.
  #pragma unroll
  for (int it = 0; it < 4; ++it) {
    const int pair = it * 256 + t;           // b*64 + pl
    const int b = pair >> 6;
    const int pl = pair & 63;
    half8 v = cvt8_nt(nz2 + (size_t)(b * NPIX + p0 + pl) * 8);
    *(half8*)(n2p + (p0 + pl) * 128 + b * 8) = v;
  }
  __syncthreads();
  #pragma unroll
  for (int it = 0; it < 8; ++it) {
    const int idx = it * 256 + t;
    const int px = idx >> 5;
    const int c = idx & 31;
    ushort8 v = *(const ushort8*)&tile[px][c * 8];
    *(ushort8*)(outf + (p0 + px) * 256 + c * 8) = v;  // cached: re-read by lr_fused
  }
}

// Fused einsum + MLP, wmap staged via global_load_lds (no VGPR landing zone).
// One wave per pixel; 4 waves (4 px) per block, grid 4096.
// Per wave: 9 x global_load_lds_dwordx4 stage the pixel's full 9 KB wmap slice
// into a wave-private LDS tile -> 9 KB in flight per wave (vs ~0.5 KB with VGPR
// destinations), decoupling HBM BW from register pressure.
// einsum: D[b][m] = sum_{k,n} feats[b][nb(p,k)][n] * wmap[p][k][m][n]  (K=144 pad 160)
// MFMA f32_16x16x32_f16: A[i=lane&15][k=q*8+j], B[j=lane&15][k], D: col=lane&15, row=q*4+r.
__global__ __launch_bounds__(256, 4) void lr_fused(
    const f16*  __restrict__ feats,   // [NPIX][16][16] f16 (ws)
    const f16*  __restrict__ n2p,     // [NPIX][16][8] f16 (ws)
    const float* __restrict__ wmap,   // [NPIX][9][16][16] f32
    const int*  __restrict__ nidx,    // [NPIX][9] i32
    const float* __restrict__ w1,     // [64][24] f32
    const float* __restrict__ b1,     // [64] f32
    const float* __restrict__ w2,     // [8][64] f32
    const float* __restrict__ b2,     // [8] f32
    float* __restrict__ outp)         // [16][8][NPIX] f32
{
  // Per-wave 9 KB wmap tile; tbuf/lh overlay it after the einsum consumes it
  // (wave-private region; DS ops from one wave are processed in order).
  __shared__ __align__(16) char wbuf[4][9216];
  __shared__ __align__(16) float stage[128][4];   // out tile [(b*8+f)][4 px]

  const int t = threadIdx.x;
  const int wv = t >> 6;
  const int l = t & 63;
  const int col = l & 15;
  const int q = l >> 4;

  const int bid = blockIdx.x;                               // [0, 4096)
  const int p0 = ((((bid & 7) << 9) + (bid >> 3)) << 2);    // XCD-slab swizzle
  const int p = p0 + wv;

  const int n0 = (q & 1) * 8;
  const int kh = q >> 1;

  const int ps = __builtin_amdgcn_readfirstlane(p);
  char* wtile = wbuf[wv];

  // ---- stage wmap slice: 9 chunks x 1 KB, one global_load_lds_dwordx4 each.
  // Global src is per-lane (base + l*16); LDS dest is wave-uniform base + l*16.
  {
    const char* wsrc = (const char*)(wmap + (size_t)ps * (9 * 256));
    #pragma unroll
    for (int k = 0; k < 9; ++k) {
      __builtin_amdgcn_global_load_lds(
          (const __attribute__((address_space(1))) void*)(wsrc + k * 1024 + l * 16),
          (__attribute__((address_space(3))) void*)(wtile + k * 1024),
          16, 0, 0);
    }
  }

  // ---- feats gathers (VGPR; L2-hot) ----
  int nb[9];
  #pragma unroll
  for (int k = 0; k < 9; ++k)
    nb[k] = __builtin_amdgcn_readfirstlane(nidx[ps * 9 + k]);

  half8 af[5];
  #pragma unroll
  for (int c = 0; c < 4; ++c) {
    const int k = 2 * c + kh;
    af[c] = *(const half8*)(feats + nb[k] * 256 + col * 16 + n0);
  }
  af[4] = (half8){0, 0, 0, 0, 0, 0, 0, 0};
  if (q < 2)
    af[4] = *(const half8*)(feats + nb[8] * 256 + col * 16 + n0);

  // ---- MLP preloads (independent; overlap the wmap staging latency) ----
  half8 w1f[4];
  float b1f[4];
  #pragma unroll
  for (int jc = 0; jc < 4; ++jc) {
    w1f[jc] = (half8){0, 0, 0, 0, 0, 0, 0, 0};
    if (q < 3) w1f[jc] = cvt8(w1 + (jc * 16 + col) * 24 + q * 8);
    b1f[jc] = b1[jc * 16 + col];
  }
  half8 w2f[2] = {{0, 0, 0, 0, 0, 0, 0, 0}, {0, 0, 0, 0, 0, 0, 0, 0}};
  float b2f = 0.f;
  if (col < 8) {
    w2f[0] = cvt8(w2 + col * 64 + q * 8);
    w2f[1] = cvt8(w2 + col * 64 + 32 + q * 8);
    b2f = b2[col];
  }
  half8 n2v = (half8){0, 0, 0, 0, 0, 0, 0, 0};
  if (q == 2) n2v = *(const half8*)(n2p + p * 128 + col * 8);   // coalesced, L2-hot

  // ---- drain staging (covers wmap->LDS, feats, and weight loads) ----
  asm volatile("s_waitcnt vmcnt(0)" ::: "memory");

  // ---- einsum: read B-fragments from LDS tile, MFMA ----
  // chunk k layout: float index col*16 + n; lane reads [col][n0..n0+7] = 32 B.
  half8 bfr[5];
  #pragma unroll
  for (int c = 0; c < 4; ++c) {
    const int k = 2 * c + kh;
    const f32x4* wp = (const f32x4*)(wtile + k * 1024 + col * 64 + (q & 1) * 32);
    bfr[c] = cvt8_pair(wp[0], wp[1]);
  }
  bfr[4] = (half8){0, 0, 0, 0, 0, 0, 0, 0};
  if (q < 2) {
    const f32x4* wp = (const f32x4*)(wtile + 8 * 1024 + col * 64 + (q & 1) * 32);
    bfr[4] = cvt8_pair(wp[0], wp[1]);
  }

  f32x4 acc = {0.f, 0.f, 0.f, 0.f};
  #pragma unroll
  for (int c = 0; c < 5; ++c)
    acc = __builtin_amdgcn_mfma_f32_16x16x32_f16(af[c], bfr[c], acc, 0, 0, 0);

  // ---- overlay scratch on the (now dead) wmap tile ----
  f16* tb = (f16*)wtile;            // 512 B: einsum-D transpose [b*16+m]
  f16* lh = (f16*)(wtile + 512);    // 2304 B: h [b][j], stride 72

  // D[b=q*4+r][m=col] -> tb[b*16+m]
  #pragma unroll
  for (int r = 0; r < 4; ++r)
    tb[(q * 4 + r) * 16 + col] = (f16)acc[r];

  const f32x4 zero4 = {0.f, 0.f, 0.f, 0.f};

  // ---- MLP1: K=24 pad 32, N=64 ----
  half8 amlp = n2v;                                        // q==2: noise2; q==3: zero
  if (q < 2) amlp = *(const half8*)(tb + col * 16 + q * 8);  // d0..15 (wave-private LDS)

  #pragma unroll
  for (int jc = 0; jc < 4; ++jc) {
    f32x4 h4 = __builtin_amdgcn_mfma_f32_16x16x32_f16(amlp, w1f[jc], zero4, 0, 0, 0);
    #pragma unroll
    for (int r = 0; r < 4; ++r) {
      float hv = fmaxf(h4[r] + b1f[jc], 0.f);
      lh[(q * 4 + r) * 72 + jc * 16 + col] = (f16)hv;      // wave-private, no barrier
    }
  }

  // ---- MLP2: K=64, N=8 pad 16 ----
  f32x4 oacc = zero4;
  #pragma unroll
  for (int c2 = 0; c2 < 2; ++c2) {
    half8 a2 = *(const half8*)(lh + col * 72 + c2 * 32 + q * 8);
    oacc = __builtin_amdgcn_mfma_f32_16x16x32_f16(a2, w2f[c2], oacc, 0, 0, 0);
  }
  if (col < 8) {
    #pragma unroll
    for (int r = 0; r < 4; ++r) {
      const int row = q * 32 + r * 8 + col;   // b*8 + f
      stage[row][wv] = oacc[r] + b2f;
    }
  }

  __syncthreads();

  // ---- cooperative write-out: 128 rows x 4 px; 8 B stores merge in L2
  // (consecutive-p blocks live on the same XCD slab -> same L2 -> full lines) ----
  {
    const int row = t >> 1;
    const int h2 = (t & 1) * 2;
    f32x2 v = *(const f32x2*)&stage[row][h2];
    *(f32x2*)(outp + row * NPIX + p0 + h2) = v;
  }
}

extern "C" void kernel_launch(void* const* d_in, const int* in_sizes, int n_in,
                              void* d_out, int out_size, void* d_ws, size_t ws_size,
                              hipStream_t stream) {
  const float* y    = (const float*)d_in[0];
  const float* nz   = (const float*)d_in[1];
  const float* nz2  = (const float*)d_in[2];
  const float* wmap = (const float*)d_in[3];
  const float* w1   = (const float*)d_in[4];
  const float* b1   = (const float*)d_in[5];
  const float* w2   = (const float*)d_in[6];
  const float* b2   = (const float*)d_in[7];
  const int* nidx   = (const int*)d_in[8];
  float* outp = (float*)d_out;
  f16* feats = (f16*)d_ws;                                        // 8 MB
  f16* n2p   = (f16*)((char*)d_ws + (size_t)NPIX * 256 * 2);      // 4 MB

  hipLaunchKernelGGL(pack_feats, dim3(NPIX / 64), dim3(256), 0, stream,
                     y, nz, nz2, feats, n2p);
  hipLaunchKernelGGL(lr_fused, dim3(NPIX / 4), dim3(256), 0, stream,
                     feats, n2p, wmap, nidx, w1, b1, w2, b2, outp);
}